// Round 15
// baseline (45.603 us; speedup 1.0000x reference)
//
#include <hip/hip_runtime.h>

#define NE 8               // experts
#define H4 512             // float4 per token row (2048 floats)
#define NTOK 16384         // 4 * 4096 tokens
#define TPW 4              // tokens per wave (full K per wave)
#define TPB 16             // tokens per block (4 independent waves)
#define NBLK (NTOK / TPB)  // 1024 blocks
#define NPART (NBLK * 4)   // 4096 per-wave aux partials
#define AUX_COEF 0.01f

typedef float f4v __attribute__((ext_vector_type(4)));

// 8-leaf static-index select (rule #20: no runtime array indexing)
#define SEL8(A) ((e2 & 4) ? ((e2 & 2) ? ((e2 & 1) ? A[7] : A[6])   \
                                      : ((e2 & 1) ? A[5] : A[4]))  \
                          : ((e2 & 2) ? ((e2 & 1) ? A[3] : A[2])   \
                                      : ((e2 & 1) ? A[1] : A[0])))

// Fully per-wave fused router: each wave streams 4 tokens x full 2048 cols
// (R11's proven load structure), then finishes ENTIRELY in-wave: butterfly,
// softmax, top-2, output write, aux butterfly, per-wave partial store.
// No LDS, no __syncthreads, no cross-wave coupling anywhere.
__global__ __launch_bounds__(256, 4)
void router_fused(const float* __restrict__ hs, const float* __restrict__ gw,
                  float* __restrict__ out, float* __restrict__ ws2)
{
    const int tid  = threadIdx.x;
    const int wave = tid >> 6, lane = tid & 63;
    const int tok0 = blockIdx.x * TPB + wave * TPW;

    const f4v* __restrict__ hs4 = (const f4v*)hs;
    const f4v* __restrict__ gw4 = (const f4v*)gw;

    float acc[TPW][NE];
    #pragma unroll
    for (int r = 0; r < TPW; ++r)
        #pragma unroll
        for (int e = 0; e < NE; ++e) acc[r][e] = 0.f;

    #pragma unroll
    for (int it = 0; it < 8; ++it) {
        const int col = it * 64 + lane;
        f4v h[TPW];
        #pragma unroll
        for (int r = 0; r < TPW; ++r)
            h[r] = hs4[(size_t)(tok0 + r) * H4 + col];
        f4v g[NE];
        #pragma unroll
        for (int e = 0; e < NE; ++e) g[e] = gw4[e * H4 + col];
        #pragma unroll
        for (int r = 0; r < TPW; ++r)
            #pragma unroll
            for (int e = 0; e < NE; ++e)
                acc[r][e] += h[r].x * g[e].x + h[r].y * g[e].y
                           + h[r].z * g[e].z + h[r].w * g[e].w;
    }

    // butterfly: every lane gets the full dot for all 32 (r,e)
    #pragma unroll
    for (int r = 0; r < TPW; ++r)
        #pragma unroll
        for (int e = 0; e < NE; ++e) {
            float v = acc[r][e];
            #pragma unroll
            for (int s = 32; s > 0; s >>= 1) v += __shfl_xor(v, s, 64);
            acc[r][e] = v;
        }

    // lane (mod 4) picks its token — static indexing only
    const int ls = lane & 3;
    float lg[NE];
    #pragma unroll
    for (int e = 0; e < NE; ++e)
        lg[e] = (ls == 0) ? acc[0][e] : (ls == 1) ? acc[1][e]
              : (ls == 2) ? acc[2][e] : acc[3][e];

    float m = lg[0];
    #pragma unroll
    for (int e = 1; e < NE; ++e) m = fmaxf(m, lg[e]);
    float p[NE];
    float s = 0.f;
    #pragma unroll
    for (int e = 0; e < NE; ++e) { p[e] = __expf(lg[e] - m); s += p[e]; }
    const float inv = 1.f / s;

    // top-2 on probs; strict '>' keeps lowest index on ties (lax.top_k order)
    float v0 = -1.f; int i0 = 0;
    #pragma unroll
    for (int e = 0; e < NE; ++e) { if (p[e] > v0) { v0 = p[e]; i0 = e; } }
    float v1 = -1.f; int i1 = 0;
    #pragma unroll
    for (int e = 0; e < NE; ++e) { if (e != i0 && p[e] > v1) { v1 = p[e]; i1 = e; } }

    // lanes 0-3 write their token's outputs (ls == lane there)
    if (lane < TPW) {
        const int tok = tok0 + ls;
        float2* __restrict__ o2 = (float2*)out;
        const float wsum = v0 + v1;
        o2[tok]        = make_float2(v0 / wsum, v1 / wsum);
        o2[NTOK + tok] = make_float2((float)i0, (float)i1);
    }

    // in-wave aux reduction: each token appears on 16 lanes -> sum/16
    float q[NE], c[NE];
    #pragma unroll
    for (int e = 0; e < NE; ++e) {
        q[e] = p[e] * inv;
        c[e] = ((i0 == e) ? 1.f : 0.f) + ((i1 == e) ? 1.f : 0.f);
    }
    #pragma unroll
    for (int e = 0; e < NE; ++e) {
        #pragma unroll
        for (int sh = 32; sh > 0; sh >>= 1) {
            q[e] += __shfl_xor(q[e], sh, 64);
            c[e] += __shfl_xor(c[e], sh, 64);
        }
    }
    // lanes 0-15 store the per-wave partial row (coalesced 64 B)
    if (lane < 16) {
        const int e2 = lane & 7;
        const float val = (lane < 8) ? SEL8(q) : SEL8(c);
        ws2[((size_t)blockIdx.x * 4 + wave) * 16 + lane] = val * 0.0625f;
    }
}

// Reduce 4096 x 16 per-wave partials -> aux scalar. 1024 threads:
// (row 0..63, e 0..15) each sums 64 entries, in-wave shuffle folds 4 rows,
// LDS folds 16 waves.
__global__ __launch_bounds__(1024)
void router_aux2(const float* __restrict__ ws2, float* __restrict__ out)
{
    __shared__ float red[16][16];
    __shared__ float tot[16];
    const int tid = threadIdx.x;
    const int e = tid & 15;
    const int row = tid >> 4;                // 0..63
    float s = 0.f;
    #pragma unroll 8
    for (int j = 0; j < NPART / 64; ++j)     // 64 entries, fully coalesced
        s += ws2[(size_t)(row + 64 * j) * 16 + e];
    // wave covers 4 rows x 16 e: fold rows via shuffle
    s += __shfl_xor(s, 16, 64);
    s += __shfl_xor(s, 32, 64);
    const int wv = tid >> 6, lane = tid & 63;
    if (lane < 16) red[wv][lane] = s;
    __syncthreads();
    if (tid < 16) {
        float t2 = 0.f;
        #pragma unroll
        for (int w = 0; w < 16; ++w) t2 += red[w][tid];
        tot[tid] = t2;
    }
    __syncthreads();
    if (tid == 0) {
        float s2 = 0.f;
        #pragma unroll
        for (int e2 = 0; e2 < NE; ++e2) {
            const float ef = tot[NE + e2] / (float)(NTOK * 2);  // expert_frac
            const float rf = tot[e2] / (float)NTOK;             // router_frac
            s2 += ef * rf;
        }
        out[4 * NTOK] = (float)NE * s2 * AUX_COEF;
    }
}

extern "C" void kernel_launch(void* const* d_in, const int* in_sizes, int n_in,
                              void* d_out, int out_size, void* d_ws, size_t ws_size,
                              hipStream_t stream)
{
    const float* hs = (const float*)d_in[0];   // [4,4096,2048] f32
    const float* gw = (const float*)d_in[1];   // [8,2048] f32
    float* out = (float*)d_out;                // 32768 rw | 32768 idx | 1 aux
    float* ws2 = (float*)d_ws;                 // [4096][16] per-wave partials

    hipLaunchKernelGGL(router_fused, dim3(NBLK), dim3(256), 0, stream,
                       hs, gw, out, ws2);
    hipLaunchKernelGGL(router_aux2, dim3(1), dim3(1024), 0, stream, ws2, out);
}

// Round 16
// 37.701 us; speedup vs baseline: 1.2096x; 1.2096x over previous
//
#include <hip/hip_runtime.h>

#define NE 8               // experts
#define H4 512             // float4 per token row (2048 floats)
#define NTOK 16384         // 4 * 4096 tokens
#define TPW 4              // tokens per wave (full K per wave)
#define TPB 16             // tokens per block (4 independent waves)
#define NBLK_A (NTOK / TPB)  // 1024 blocks
#define NBLK_B 64          // finish-kernel blocks (16384 / 256)
#define AUX_COEF 0.01f

// ws layout (floats): part[NTOK][NE] = 131072 | ws2[NBLK_B*16]
#define WS2_OFF (NTOK * NE)

typedef float f4v __attribute__((ext_vector_type(4)));

// 8-leaf static-index select (rule #20: no runtime array indexing)
#define SEL8(A) ((e2 & 4) ? ((e2 & 2) ? ((e2 & 1) ? A[7] : A[6])   \
                                      : ((e2 & 1) ? A[5] : A[4]))  \
                          : ((e2 & 2) ? ((e2 & 1) ? A[3] : A[2])   \
                                      : ((e2 & 1) ? A[1] : A[0])))

// Kernel A (hot): QK=1 streaming GEMV — each wave does 4 tokens x full
// 2048 cols. Pure streaming + butterfly + one 128 B store per wave.
// No LDS, no barriers, no softmax tail in the hot loop.
__global__ __launch_bounds__(256, 4)
void router_partial(const float* __restrict__ hs, const float* __restrict__ gw,
                    float* __restrict__ part)
{
    const int tid  = threadIdx.x;
    const int wave = tid >> 6, lane = tid & 63;
    const int tok0 = blockIdx.x * TPB + wave * TPW;

    const f4v* __restrict__ hs4 = (const f4v*)hs;
    const f4v* __restrict__ gw4 = (const f4v*)gw;

    float acc[TPW][NE];
    #pragma unroll
    for (int r = 0; r < TPW; ++r)
        #pragma unroll
        for (int e = 0; e < NE; ++e) acc[r][e] = 0.f;

    #pragma unroll
    for (int it = 0; it < 8; ++it) {
        const int col = it * 64 + lane;
        f4v h[TPW];
        #pragma unroll
        for (int r = 0; r < TPW; ++r)
            h[r] = hs4[(size_t)(tok0 + r) * H4 + col];
        f4v g[NE];
        #pragma unroll
        for (int e = 0; e < NE; ++e) g[e] = gw4[e * H4 + col];
        #pragma unroll
        for (int r = 0; r < TPW; ++r)
            #pragma unroll
            for (int e = 0; e < NE; ++e)
                acc[r][e] += h[r].x * g[e].x + h[r].y * g[e].y
                           + h[r].z * g[e].z + h[r].w * g[e].w;
    }

    // butterfly: every lane gets the full dot for all 32 (r,e)
    #pragma unroll
    for (int r = 0; r < TPW; ++r)
        #pragma unroll
        for (int e = 0; e < NE; ++e) {
            float v = acc[r][e];
            #pragma unroll
            for (int s = 32; s > 0; s >>= 1) v += __shfl_xor(v, s, 64);
            acc[r][e] = v;
        }

    // lanes 0..31 store one (token,expert) logit -> 128 B coalesced/wave
    const int r2 = (lane >> 3) & 3, e2 = lane & 7;
    const float v = (r2 & 2) ? ((r2 & 1) ? SEL8(acc[3]) : SEL8(acc[2]))
                             : ((r2 & 1) ? SEL8(acc[1]) : SEL8(acc[0]));
    if (lane < 32)
        part[(size_t)(tok0 + r2) * NE + e2] = v;
}

// Kernel B: one thread per token. Read its 8 logits (32 B), softmax +
// top-2 + renorm, coalesced float2 outputs, per-block aux partial.
__global__ __launch_bounds__(256)
void router_finish(const float* __restrict__ part, float* __restrict__ out,
                   float* __restrict__ ws2)
{
    __shared__ float red[4][2 * NE];
    const int tid = threadIdx.x;
    const int t   = blockIdx.x * 256 + tid;      // token
    const float4* __restrict__ p4 = (const float4*)part;

    float lg[NE];
    {
        float4 a = p4[(size_t)t * 2],  b = p4[(size_t)t * 2 + 1];
        lg[0]=a.x; lg[1]=a.y; lg[2]=a.z; lg[3]=a.w;
        lg[4]=b.x; lg[5]=b.y; lg[6]=b.z; lg[7]=b.w;
    }

    float m = lg[0];
    #pragma unroll
    for (int e = 1; e < NE; ++e) m = fmaxf(m, lg[e]);
    float p[NE];
    float s = 0.f;
    #pragma unroll
    for (int e = 0; e < NE; ++e) { p[e] = __expf(lg[e] - m); s += p[e]; }
    const float inv = 1.f / s;

    // top-2 on probs; strict '>' keeps lowest index on ties (lax.top_k order)
    float v0 = -1.f; int i0 = 0;
    #pragma unroll
    for (int e = 0; e < NE; ++e) { if (p[e] > v0) { v0 = p[e]; i0 = e; } }
    float v1 = -1.f; int i1 = 0;
    #pragma unroll
    for (int e = 0; e < NE; ++e) { if (e != i0 && p[e] > v1) { v1 = p[e]; i1 = e; } }

    float2* __restrict__ o2 = (float2*)out;
    const float wsum = v0 + v1;
    o2[t]        = make_float2(v0 / wsum, v1 / wsum);
    o2[NTOK + t] = make_float2((float)i0, (float)i1);

    // aux partials: every thread owns exactly one token
    float qv[NE], c[NE];
    #pragma unroll
    for (int e = 0; e < NE; ++e) {
        qv[e] = p[e] * inv;
        c[e]  = ((i0 == e) ? 1.f : 0.f) + ((i1 == e) ? 1.f : 0.f);
    }
    #pragma unroll
    for (int e = 0; e < NE; ++e) {
        #pragma unroll
        for (int sh = 32; sh > 0; sh >>= 1) {
            qv[e] += __shfl_xor(qv[e], sh, 64);
            c[e]  += __shfl_xor(c[e],  sh, 64);
        }
    }
    const int wave = tid >> 6, lane = tid & 63;
    if (lane == 0) {
        #pragma unroll
        for (int e = 0; e < NE; ++e) {
            red[wave][e]      = qv[e];
            red[wave][NE + e] = c[e];
        }
    }
    __syncthreads();
    if (tid < 2 * NE) {
        float sum = red[0][tid] + red[1][tid] + red[2][tid] + red[3][tid];
        ws2[blockIdx.x * 2 * NE + tid] = sum;
    }
}

// Kernel C: reduce 64 x 16 partials -> aux scalar
__global__ __launch_bounds__(128)
void router_aux2(const float* __restrict__ ws2, float* __restrict__ out)
{
    __shared__ float red[8][16];
    __shared__ float tot[16];
    const int tid = threadIdx.x;
    const int e = tid & 15, row = tid >> 4;      // 8 rows x 16
    float s = 0.f;
    #pragma unroll
    for (int k = 0; k < NBLK_B / 8; ++k)
        s += ws2[(row * (NBLK_B / 8) + k) * 16 + e];
    red[row][e] = s;
    __syncthreads();
    if (tid < 16) {
        float t2 = 0.f;
        #pragma unroll
        for (int r = 0; r < 8; ++r) t2 += red[r][tid];
        tot[tid] = t2;
    }
    __syncthreads();
    if (tid == 0) {
        float s2 = 0.f;
        #pragma unroll
        for (int e2 = 0; e2 < NE; ++e2) {
            const float ef = tot[NE + e2] / (float)(NTOK * 2);  // expert_frac
            const float rf = tot[e2] / (float)NTOK;             // router_frac
            s2 += ef * rf;
        }
        out[4 * NTOK] = (float)NE * s2 * AUX_COEF;
    }
}

extern "C" void kernel_launch(void* const* d_in, const int* in_sizes, int n_in,
                              void* d_out, int out_size, void* d_ws, size_t ws_size,
                              hipStream_t stream)
{
    const float* hs = (const float*)d_in[0];   // [4,4096,2048] f32
    const float* gw = (const float*)d_in[1];   // [8,2048] f32
    float* out  = (float*)d_out;               // 32768 rw | 32768 idx | 1 aux
    float* part = (float*)d_ws;                // [16384][8] logits
    float* ws2  = (float*)d_ws + WS2_OFF;      // [64][16] aux partials

    hipLaunchKernelGGL(router_partial, dim3(NBLK_A), dim3(256), 0,
                       stream, hs, gw, part);
    hipLaunchKernelGGL(router_finish, dim3(NBLK_B), dim3(256), 0,
                       stream, part, out, ws2);
    hipLaunchKernelGGL(router_aux2, dim3(1), dim3(128), 0, stream, ws2, out);
}